// Round 5
// baseline (519.342 us; speedup 1.0000x reference)
//
#include <hip/hip_runtime.h>
#include <hip/hip_bf16.h>

#define EPS 1e-6f

typedef float f32x4 __attribute__((ext_vector_type(4)));
typedef __bf16 bf16x8 __attribute__((ext_vector_type(8)));
typedef short short8 __attribute__((ext_vector_type(8)));

static __device__ __forceinline__ short bf16bits(float x) {
    __hip_bfloat16 h = __float2bfloat16(x);
    short s;
    __builtin_memcpy(&s, &h, 2);
    return s;
}
static __device__ __forceinline__ float bf16back(float x) {
    __hip_bfloat16 h = __float2bfloat16(x);
    return __bfloat162float(h);
}

// ---- Kernel A: softmax + P01/P23 pair products (+transposed/swizzled/split)
__global__ __launch_bounds__(256) void kA(const float* __restrict__ logits,
                                          const float* __restrict__ y_true,
                                          float* __restrict__ P01,
                                          float* __restrict__ P23,
                                          float* __restrict__ P01T,
                                          short* __restrict__ P23s_hi,
                                          short* __restrict__ P23s_lo,
                                          int* __restrict__ label) {
    __shared__ float row[64];
    int b = blockIdx.x, t = threadIdx.x;
    if (t < 64) {
        float x = logits[b * 64 + t];
        float m = x;
        for (int mk = 8; mk >= 1; mk >>= 1) m = fmaxf(m, __shfl_xor(m, mk, 16));
        float e = __expf(x - m);
        float s = e;
        for (int mk = 8; mk >= 1; mk >>= 1) s += __shfl_xor(s, mk, 16);
        row[t] = e / s;
    }
    if (t >= 128 && t < 228) {
        int y = t - 128;
        if (y_true[b * 100 + y] > 0.5f) label[b] = y;
    }
    __syncthreads();
    int hi = t >> 4, lo = t & 15;
    float v01 = row[hi] * row[16 + lo];
    float v23 = row[32 + hi] * row[48 + lo];
    P01[b * 256 + t] = v01;
    P01T[t * 1024 + b] = v01;
    P23[b * 256 + t] = v23;
    float hf = bf16back(v23);
    int ts = t ^ ((b & 7) << 3);   // XOR swizzle (matches kC LDS read)
    P23s_hi[b * 256 + ts] = bf16bits(v23);
    P23s_lo[b * 256 + ts] = bf16bits(v23 - hf);
}

// ---- Kernel S: deterministic counting sort of b by label -------------------
__global__ __launch_bounds__(1024) void kS(const int* __restrict__ label,
                                           int* __restrict__ bidx,
                                           int* __restrict__ ylab) {
    __shared__ int lab[1024];
    __shared__ int offs[101];
    int t = threadIdx.x;
    lab[t] = label[t];
    __syncthreads();
    if (t <= 100) {
        int c = 0;
        for (int b = 0; b < 1024; ++b) c += (lab[b] < t) ? 1 : 0;
        offs[t] = c;
    }
    __syncthreads();
    int my = lab[t];
    int rank = 0;
    for (int b = 0; b < t; ++b) rank += (lab[b] == my) ? 1 : 0;
    int pos = offs[my] + rank;
    bidx[pos] = t;
    ylab[pos] = my;
}

// ---- Kernel B: segmented accumulation -> pyT_hi/lo [y][65536] bf16 ---------
// 1024 threads: 4 b-groups of 256 sorted rows; LDS atomic merge.
__global__ __launch_bounds__(1024) void kB(const float* __restrict__ P01,
                                           const float* __restrict__ P23,
                                           const int* __restrict__ bidx,
                                           const int* __restrict__ ylab,
                                           short* __restrict__ pyT_hi,
                                           short* __restrict__ pyT_lo) {
    __shared__ float numy[100 * 257];
    __shared__ float aA[1024];
    __shared__ int blist[1024];
    __shared__ unsigned char yl[1024];
    __shared__ float numjl[4][256];
    int t = threadIdx.x;
    int u = blockIdx.x;

    {
        int b = bidx[t];
        blist[t] = b;
        aA[t] = P01[b * 256 + u];
        yl[t] = (unsigned char)ylab[t];
    }
    for (int i = t; i < 100 * 257; i += 1024) numy[i] = 0.f;
    __syncthreads();

    int g = t >> 8;       // group 0..3
    int tc = t & 255;     // t-column
    int i0 = g << 8;

    float numj = 0.f, acc = 0.f;
    int ycur = yl[i0];
    float v[8];
    #pragma unroll
    for (int k = 0; k < 8; ++k) v[k] = P23[blist[i0 + k] * 256 + tc];

    for (int c = 0; c < 32; ++c) {
        float w[8];
        if (c < 31) {
            #pragma unroll
            for (int k = 0; k < 8; ++k) w[k] = P23[blist[i0 + (c + 1) * 8 + k] * 256 + tc];
        }
        #pragma unroll
        for (int k = 0; k < 8; ++k) {
            int i = i0 + c * 8 + k;
            int y = yl[i];
            if (y != ycur) {
                atomicAdd(&numy[ycur * 257 + tc], acc);
                numj += acc;
                acc = 0.f;
                ycur = y;
            }
            acc = fmaf(aA[i], v[k], acc);
        }
        if (c < 31) {
            #pragma unroll
            for (int k = 0; k < 8; ++k) v[k] = w[k];
        }
    }
    atomicAdd(&numy[ycur * 257 + tc], acc);
    numj += acc;
    numjl[g][tc] = numj;
    __syncthreads();

    // write pyT hi/lo: [y][u*256 + t], packed 2 t's per u32 store
    for (int it = 0; it < 16; ++it) {
        int idx = it * 1024 + t;      // 0..16383
        int y = idx >> 7;             // 0..127
        int t0 = (idx & 127) << 1;
        float v0 = 0.f, v1 = 0.f;
        if (y < 100) {
            float nj0 = fmaxf(numjl[0][t0] + numjl[1][t0] + numjl[2][t0] + numjl[3][t0], EPS);
            float nj1 = fmaxf(numjl[0][t0 + 1] + numjl[1][t0 + 1] + numjl[2][t0 + 1] + numjl[3][t0 + 1], EPS);
            v0 = fminf(fmaxf(numy[y * 257 + t0], EPS) / nj0, 1.0f);
            v1 = fminf(fmaxf(numy[y * 257 + t0 + 1], EPS) / nj1, 1.0f);
        }
        unsigned h0 = (unsigned short)bf16bits(v0);
        unsigned h1 = (unsigned short)bf16bits(v1);
        unsigned l0 = (unsigned short)bf16bits(v0 - bf16back(v0));
        unsigned l1 = (unsigned short)bf16bits(v1 - bf16back(v1));
        size_t ei = ((size_t)y * 65536 + (size_t)u * 256 + t0) >> 1;
        ((unsigned*)pyT_hi)[ei] = h0 | (h1 << 16);
        ((unsigned*)pyT_lo)[ei] = l0 | (l1 << 16);
    }
}

// ---- Kernel C: MFMA GEMM.  part[uspl][y][b] += P01[b,u]*(py_u x P23^T) -----
// block tile: 64b x 128y x 8u; grid = 16 bb x 32 uspl = 512 blocks (2/CU).
// 512 thr = 8 waves (2 wb x 4 wy), wave tile 32b x 32y (m=2, n=2).
// A (P23 hi/lo bf16, swizzled) in LDS (66 KB); B (pyT) streamed with a
// STATIC-named double buffer (no array indexing -> no scratch demotion).
__global__ __launch_bounds__(512, 4) void kC(const short* __restrict__ P23s_hi,
                                             const short* __restrict__ P23s_lo,
                                             const float* __restrict__ P01T,
                                             const short* __restrict__ pyT_hi,
                                             const short* __restrict__ pyT_lo,
                                             float* __restrict__ part) {
    __shared__ short Ahi[64 * 256];
    __shared__ short Alo[64 * 256];
    __shared__ float p01s[8 * 64];
    int t = threadIdx.x;
    int bb = blockIdx.x >> 5, uspl = blockIdx.x & 31;
    int bbase = bb << 6;
    int u0 = uspl << 3;

    #pragma unroll
    for (int r = 0; r < 4; ++r) {
        int c = r * 512 + t;   // short8 chunk 0..2047
        *(short8*)(Ahi + c * 8) = *(const short8*)(P23s_hi + bbase * 256 + c * 8);
        *(short8*)(Alo + c * 8) = *(const short8*)(P23s_lo + bbase * 256 + c * 8);
    }
    p01s[t & 511] = P01T[(u0 + ((t & 511) >> 6)) * 1024 + bbase + (t & 63)];
    __syncthreads();

    int lane = t & 63;
    int wave = t >> 6;
    int wb = wave >> 2, wy = wave & 3;
    int l15 = lane & 15, l4 = lane >> 4;
    int hi8 = l4 << 3;

    int rowA0 = wb * 32 + l15;
    int swz = (rowA0 & 7) << 3;            // same for rowA0+16
    const short* pA0h = Ahi + rowA0 * 256;
    const short* pA0l = Alo + rowA0 * 256;
    const short* pA1h = pA0h + 16 * 256;
    const short* pA1l = pA0l + 16 * 256;

    int y0 = wy * 32 + l15;
    const short* bh0 = pyT_hi + (size_t)y0 * 65536 + hi8;
    const short* bl0 = pyT_lo + (size_t)y0 * 65536 + hi8;
    const short* bh1 = bh0 + 16 * 65536;
    const short* bl1 = bl0 + 16 * 65536;

    const f32x4 zero4 = {0.f, 0.f, 0.f, 0.f};
    f32x4 P00 = zero4, P01v = zero4, P10 = zero4, P11 = zero4;
    f32x4 Q00, Q01, Q10, Q11;
    bf16x8 Bh0_0, Bh0_1, Bl0_0, Bl0_1;
    bf16x8 Bh1_0, Bh1_1, Bl1_0, Bl1_1;

#define LOADB(H0, H1, L0, L1, S)                                  \
    {                                                             \
        int off_ = (u0 + ((S) >> 3)) * 256 + ((S) & 7) * 32;      \
        H0 = *(const bf16x8*)(bh0 + off_);                        \
        H1 = *(const bf16x8*)(bh1 + off_);                        \
        L0 = *(const bf16x8*)(bl0 + off_);                        \
        L1 = *(const bf16x8*)(bl1 + off_);                        \
    }

#define COMPUTE(H0, H1, L0, L1, S)                                               \
    {                                                                            \
        const int ks_ = (S) & 7;                                                 \
        int aoff = (ks_ * 32 + hi8) ^ swz;                                       \
        bf16x8 a0h = *(const bf16x8*)(pA0h + aoff);                              \
        bf16x8 a0l = *(const bf16x8*)(pA0l + aoff);                              \
        bf16x8 a1h = *(const bf16x8*)(pA1h + aoff);                              \
        bf16x8 a1l = *(const bf16x8*)(pA1l + aoff);                              \
        f32x4 c00 = (ks_ == 0) ? zero4 : Q00;                                    \
        f32x4 c01 = (ks_ == 0) ? zero4 : Q01;                                    \
        f32x4 c10 = (ks_ == 0) ? zero4 : Q10;                                    \
        f32x4 c11 = (ks_ == 0) ? zero4 : Q11;                                    \
        c00 = __builtin_amdgcn_mfma_f32_16x16x32_bf16(a0h, H0, c00, 0, 0, 0);    \
        c10 = __builtin_amdgcn_mfma_f32_16x16x32_bf16(a1h, H0, c10, 0, 0, 0);    \
        c01 = __builtin_amdgcn_mfma_f32_16x16x32_bf16(a0h, H1, c01, 0, 0, 0);    \
        c11 = __builtin_amdgcn_mfma_f32_16x16x32_bf16(a1h, H1, c11, 0, 0, 0);    \
        c00 = __builtin_amdgcn_mfma_f32_16x16x32_bf16(a0h, L0, c00, 0, 0, 0);    \
        c10 = __builtin_amdgcn_mfma_f32_16x16x32_bf16(a1h, L0, c10, 0, 0, 0);    \
        c01 = __builtin_amdgcn_mfma_f32_16x16x32_bf16(a0h, L1, c01, 0, 0, 0);    \
        c11 = __builtin_amdgcn_mfma_f32_16x16x32_bf16(a1h, L1, c11, 0, 0, 0);    \
        c00 = __builtin_amdgcn_mfma_f32_16x16x32_bf16(a0l, H0, c00, 0, 0, 0);    \
        c10 = __builtin_amdgcn_mfma_f32_16x16x32_bf16(a1l, H0, c10, 0, 0, 0);    \
        c01 = __builtin_amdgcn_mfma_f32_16x16x32_bf16(a0l, H1, c01, 0, 0, 0);    \
        c11 = __builtin_amdgcn_mfma_f32_16x16x32_bf16(a1l, H1, c11, 0, 0, 0);    \
        Q00 = c00; Q01 = c01; Q10 = c10; Q11 = c11;                              \
        if (ks_ == 7) {                                                          \
            const int uu_ = (S) >> 3;                                            \
            f32x4 pv0 = *(const f32x4*)(p01s + uu_ * 64 + wb * 32 + (l4 << 2));  \
            f32x4 pv1 = *(const f32x4*)(p01s + uu_ * 64 + wb * 32 + 16 + (l4 << 2)); \
            P00 += pv0 * Q00; P01v += pv0 * Q01;                                 \
            P10 += pv1 * Q10; P11 += pv1 * Q11;                                  \
        }                                                                        \
    }

    LOADB(Bh0_0, Bh0_1, Bl0_0, Bl0_1, 0)
    #pragma unroll
    for (int s = 0; s < 64; s += 2) {
        LOADB(Bh1_0, Bh1_1, Bl1_0, Bl1_1, s + 1)
        COMPUTE(Bh0_0, Bh0_1, Bl0_0, Bl0_1, s)
        if (s + 2 < 64) {
            LOADB(Bh0_0, Bh0_1, Bl0_0, Bl0_1, s + 2)
        }
        COMPUTE(Bh1_0, Bh1_1, Bl1_0, Bl1_1, s + 1)
    }
#undef LOADB
#undef COMPUTE

    size_t pbase = (size_t)uspl * 128 * 1024;
    {
        int bg0 = bbase + wb * 32 + (l4 << 2);
        int bg1 = bg0 + 16;
        *(f32x4*)(part + pbase + (size_t)y0 * 1024 + bg0) = P00;
        *(f32x4*)(part + pbase + (size_t)y0 * 1024 + bg1) = P10;
        *(f32x4*)(part + pbase + (size_t)(y0 + 16) * 1024 + bg0) = P01v;
        *(f32x4*)(part + pbase + (size_t)(y0 + 16) * 1024 + bg1) = P11;
    }
}

// ---- Kernel D: reduce 32 u-split partials -> out[b*100+y] ------------------
__global__ __launch_bounds__(256) void kD(const float* __restrict__ part,
                                          float* __restrict__ out) {
    int t = threadIdx.x;
    int y = blockIdx.x >> 2;
    int b = ((blockIdx.x & 3) << 8) + t;
    float s = 0.f;
    for (int q = 0; q < 32; ++q)
        s += part[(((size_t)q * 128 + y) << 10) + b];
    out[(size_t)b * 100 + y] = s;
}

extern "C" void kernel_launch(void* const* d_in, const int* in_sizes, int n_in,
                              void* d_out, int out_size, void* d_ws, size_t ws_size,
                              hipStream_t stream) {
    const float* logits = (const float*)d_in[0];
    const float* y_true = (const float*)d_in[1];
    float* out = (float*)d_out;

    char* ws = (char*)d_ws;
    float* P01    = (float*)(ws);                        // 1 MB
    float* P23    = (float*)(ws + (1u << 20));           // 1 MB
    float* P01T   = (float*)(ws + (2u << 20));           // 1 MB
    short* P23s_hi = (short*)(ws + (3u << 20));          // 512 KB
    short* P23s_lo = (short*)(ws + (3u << 20) + (512u << 10)); // 512 KB
    int*   lab    = (int*)(ws + (4u << 20));             // 4 KB
    int*   bidx   = (int*)(ws + (4u << 20) + 4096);
    int*   ylab   = (int*)(ws + (4u << 20) + 8192);
    short* pyT_hi = (short*)(ws + (8u << 20));           // 16 MB
    short* pyT_lo = (short*)(ws + (24u << 20));          // 16 MB
    float* part   = (float*)(ws + (40u << 20));          // 16 MB

    kA<<<1024, 256, 0, stream>>>(logits, y_true, P01, P23, P01T, P23s_hi, P23s_lo, lab);
    kS<<<1, 1024, 0, stream>>>(lab, bidx, ylab);
    kB<<<256, 1024, 0, stream>>>(P01, P23, bidx, ylab, pyT_hi, pyT_lo);
    kC<<<512, 512, 0, stream>>>(P23s_hi, P23s_lo, P01T, pyT_hi, pyT_lo, part);
    kD<<<400, 256, 0, stream>>>(part, out);
}

// Round 6
// 240.862 us; speedup vs baseline: 2.1562x; 2.1562x over previous
//
#include <hip/hip_runtime.h>
#include <hip/hip_bf16.h>

#define EPS 1e-6f

typedef float f32x4 __attribute__((ext_vector_type(4)));
typedef __bf16 bf16x8 __attribute__((ext_vector_type(8)));
typedef short short8 __attribute__((ext_vector_type(8)));

static __device__ __forceinline__ short bf16bits(float x) {
    __hip_bfloat16 h = __float2bfloat16(x);
    short s;
    __builtin_memcpy(&s, &h, 2);
    return s;
}
static __device__ __forceinline__ float bf16back(float x) {
    __hip_bfloat16 h = __float2bfloat16(x);
    return __bfloat162float(h);
}

// ---- Kernel A: softmax + P01/P23 pair products (+transposed/swizzled/split)
__global__ __launch_bounds__(256) void kA(const float* __restrict__ logits,
                                          const float* __restrict__ y_true,
                                          float* __restrict__ P01,
                                          float* __restrict__ P23,
                                          float* __restrict__ P01T,
                                          short* __restrict__ P23s_hi,
                                          short* __restrict__ P23s_lo,
                                          int* __restrict__ label) {
    __shared__ float row[64];
    int b = blockIdx.x, t = threadIdx.x;
    if (t < 64) {
        float x = logits[b * 64 + t];
        float m = x;
        for (int mk = 8; mk >= 1; mk >>= 1) m = fmaxf(m, __shfl_xor(m, mk, 16));
        float e = __expf(x - m);
        float s = e;
        for (int mk = 8; mk >= 1; mk >>= 1) s += __shfl_xor(s, mk, 16);
        row[t] = e / s;
    }
    if (t >= 128 && t < 228) {
        int y = t - 128;
        if (y_true[b * 100 + y] > 0.5f) label[b] = y;
    }
    __syncthreads();
    int hi = t >> 4, lo = t & 15;
    float v01 = row[hi] * row[16 + lo];
    float v23 = row[32 + hi] * row[48 + lo];
    P01[b * 256 + t] = v01;
    P01T[t * 1024 + b] = v01;
    P23[b * 256 + t] = v23;
    float hf = bf16back(v23);
    int ts = t ^ ((b & 7) << 3);   // XOR swizzle (matches kC LDS read)
    P23s_hi[b * 256 + ts] = bf16bits(v23);
    P23s_lo[b * 256 + ts] = bf16bits(v23 - hf);
}

// ---- Kernel S: deterministic counting sort of b by label -------------------
__global__ __launch_bounds__(1024) void kS(const int* __restrict__ label,
                                           int* __restrict__ bidx,
                                           int* __restrict__ ylab) {
    __shared__ int lab[1024];
    __shared__ int offs[101];
    int t = threadIdx.x;
    lab[t] = label[t];
    __syncthreads();
    if (t <= 100) {
        int c = 0;
        for (int b = 0; b < 1024; ++b) c += (lab[b] < t) ? 1 : 0;
        offs[t] = c;
    }
    __syncthreads();
    int my = lab[t];
    int rank = 0;
    for (int b = 0; b < t; ++b) rank += (lab[b] == my) ? 1 : 0;
    int pos = offs[my] + rank;
    bidx[pos] = t;
    ylab[pos] = my;
}

// ---- Kernel B: segmented accumulation -> pyT_hi [y][65536] bf16 ------------
// 1024 threads: 4 b-groups of 256 sorted rows; LDS atomic merge.
__global__ __launch_bounds__(1024) void kB(const float* __restrict__ P01,
                                           const float* __restrict__ P23,
                                           const int* __restrict__ bidx,
                                           const int* __restrict__ ylab,
                                           short* __restrict__ pyT_hi) {
    __shared__ float numy[100 * 257];
    __shared__ float aA[1024];
    __shared__ int blist[1024];
    __shared__ unsigned char yl[1024];
    __shared__ float numjl[4][256];
    int t = threadIdx.x;
    int u = blockIdx.x;

    {
        int b = bidx[t];
        blist[t] = b;
        aA[t] = P01[b * 256 + u];
        yl[t] = (unsigned char)ylab[t];
    }
    for (int i = t; i < 100 * 257; i += 1024) numy[i] = 0.f;
    __syncthreads();

    int g = t >> 8;       // group 0..3
    int tc = t & 255;     // t-column
    int i0 = g << 8;

    float numj = 0.f, acc = 0.f;
    int ycur = yl[i0];
    float v[8];
    #pragma unroll
    for (int k = 0; k < 8; ++k) v[k] = P23[blist[i0 + k] * 256 + tc];

    for (int c = 0; c < 32; ++c) {
        float w[8];
        if (c < 31) {
            #pragma unroll
            for (int k = 0; k < 8; ++k) w[k] = P23[blist[i0 + (c + 1) * 8 + k] * 256 + tc];
        }
        #pragma unroll
        for (int k = 0; k < 8; ++k) {
            int i = i0 + c * 8 + k;
            int y = yl[i];
            if (y != ycur) {
                atomicAdd(&numy[ycur * 257 + tc], acc);
                numj += acc;
                acc = 0.f;
                ycur = y;
            }
            acc = fmaf(aA[i], v[k], acc);
        }
        if (c < 31) {
            #pragma unroll
            for (int k = 0; k < 8; ++k) v[k] = w[k];
        }
    }
    atomicAdd(&numy[ycur * 257 + tc], acc);
    numj += acc;
    numjl[g][tc] = numj;
    __syncthreads();

    // write pyT hi: [y][u*256 + t], packed 2 t's per u32 store
    for (int it = 0; it < 16; ++it) {
        int idx = it * 1024 + t;      // 0..16383
        int y = idx >> 7;             // 0..127
        int t0 = (idx & 127) << 1;
        float v0 = 0.f, v1 = 0.f;
        if (y < 100) {
            float nj0 = fmaxf(numjl[0][t0] + numjl[1][t0] + numjl[2][t0] + numjl[3][t0], EPS);
            float nj1 = fmaxf(numjl[0][t0 + 1] + numjl[1][t0 + 1] + numjl[2][t0 + 1] + numjl[3][t0 + 1], EPS);
            v0 = fminf(fmaxf(numy[y * 257 + t0], EPS) / nj0, 1.0f);
            v1 = fminf(fmaxf(numy[y * 257 + t0 + 1], EPS) / nj1, 1.0f);
        }
        unsigned h0 = (unsigned short)bf16bits(v0);
        unsigned h1 = (unsigned short)bf16bits(v1);
        size_t ei = ((size_t)y * 65536 + (size_t)u * 256 + t0) >> 1;
        ((unsigned*)pyT_hi)[ei] = h0 | (h1 << 16);
    }
}

// ---- Kernel C: MFMA GEMM.  part[uspl][y][b] += P01[b,u]*(py_u x P23^T) -----
// block tile: 64b x 128y x 8u; grid = 16 bb x 32 uspl = 512 blocks (2/CU).
// 512 thr = 8 waves (2 wb x 4 wy), wave tile 32b x 32y.
// A = P23 hi/lo bf16 in LDS (66 KB, swizzled); B = pyT_hi streamed from
// global with a 1-step named double buffer inside a REAL (unroll-1) uu loop
// so register live ranges stay bounded (no scratch demotion).
// Q = (A_hi + A_lo) * B_hi : 2 MFMAs per (m,n,k-step); B carries bf16 error.
__global__ __launch_bounds__(512, 4) void kC(const short* __restrict__ P23s_hi,
                                             const short* __restrict__ P23s_lo,
                                             const float* __restrict__ P01T,
                                             const short* __restrict__ pyT_hi,
                                             float* __restrict__ part) {
    __shared__ short Ahi[64 * 256];
    __shared__ short Alo[64 * 256];
    __shared__ float p01s[8 * 64];
    int t = threadIdx.x;
    int bb = blockIdx.x >> 5, uspl = blockIdx.x & 31;
    int bbase = bb << 6;
    int u0 = uspl << 3;

    #pragma unroll
    for (int r = 0; r < 4; ++r) {
        int c = r * 512 + t;   // short8 chunk 0..2047
        *(short8*)(Ahi + c * 8) = *(const short8*)(P23s_hi + bbase * 256 + c * 8);
        *(short8*)(Alo + c * 8) = *(const short8*)(P23s_lo + bbase * 256 + c * 8);
    }
    p01s[t] = P01T[(u0 + (t >> 6)) * 1024 + bbase + (t & 63)];
    __syncthreads();

    int lane = t & 63;
    int wave = t >> 6;
    int wb = wave >> 2, wy = wave & 3;
    int l15 = lane & 15, l4 = lane >> 4;
    int hi8 = l4 << 3;

    int rowA0 = wb * 32 + l15;
    int swz = (rowA0 & 7) << 3;            // same for rowA0+16
    const short* pA0h = Ahi + rowA0 * 256;
    const short* pA0l = Alo + rowA0 * 256;
    const short* pA1h = pA0h + 16 * 256;
    const short* pA1l = pA0l + 16 * 256;

    int y0 = wy * 32 + l15;
    const short* bh0 = pyT_hi + (size_t)y0 * 65536 + hi8;
    const short* bh1 = bh0 + 16 * 65536;

    const f32x4 zero4 = {0.f, 0.f, 0.f, 0.f};
    f32x4 P00 = zero4, P01v = zero4, P10 = zero4, P11 = zero4;
    bf16x8 Ba0, Ba1, Bb0, Bb1;   // named 1-step double buffer (2 n-tiles)

    {   // preload (uu=0, ks=0)
        int off_ = u0 * 256;
        Ba0 = *(const bf16x8*)(bh0 + off_);
        Ba1 = *(const bf16x8*)(bh1 + off_);
    }

#define STEP(CUR0, CUR1, NXT0, NXT1, KS, NOFF)                                   \
    {                                                                            \
        NXT0 = *(const bf16x8*)(bh0 + (NOFF));                                   \
        NXT1 = *(const bf16x8*)(bh1 + (NOFF));                                   \
        int aoff = ((KS) * 32 + hi8) ^ swz;                                      \
        bf16x8 a0h = *(const bf16x8*)(pA0h + aoff);                              \
        bf16x8 a0l = *(const bf16x8*)(pA0l + aoff);                              \
        bf16x8 a1h = *(const bf16x8*)(pA1h + aoff);                              \
        bf16x8 a1l = *(const bf16x8*)(pA1l + aoff);                              \
        f32x4 c00 = ((KS) == 0) ? zero4 : Q00;                                   \
        f32x4 c01 = ((KS) == 0) ? zero4 : Q01;                                   \
        f32x4 c10 = ((KS) == 0) ? zero4 : Q10;                                   \
        f32x4 c11 = ((KS) == 0) ? zero4 : Q11;                                   \
        c00 = __builtin_amdgcn_mfma_f32_16x16x32_bf16(a0h, CUR0, c00, 0, 0, 0);  \
        c10 = __builtin_amdgcn_mfma_f32_16x16x32_bf16(a1h, CUR0, c10, 0, 0, 0);  \
        c01 = __builtin_amdgcn_mfma_f32_16x16x32_bf16(a0h, CUR1, c01, 0, 0, 0);  \
        c11 = __builtin_amdgcn_mfma_f32_16x16x32_bf16(a1h, CUR1, c11, 0, 0, 0);  \
        c00 = __builtin_amdgcn_mfma_f32_16x16x32_bf16(a0l, CUR0, c00, 0, 0, 0);  \
        c10 = __builtin_amdgcn_mfma_f32_16x16x32_bf16(a1l, CUR0, c10, 0, 0, 0);  \
        c01 = __builtin_amdgcn_mfma_f32_16x16x32_bf16(a0l, CUR1, c01, 0, 0, 0);  \
        c11 = __builtin_amdgcn_mfma_f32_16x16x32_bf16(a1l, CUR1, c11, 0, 0, 0);  \
        Q00 = c00; Q01 = c01; Q10 = c10; Q11 = c11;                              \
    }

    #pragma unroll 1
    for (int uu = 0; uu < 8; ++uu) {
        int ub = (u0 + uu) * 256;
        int ubn = ub + 256;   // uu=7 wrap: benign in-workspace prefetch, unused
        f32x4 Q00, Q01, Q10, Q11;
        STEP(Ba0, Ba1, Bb0, Bb1, 0, ub + 32)
        STEP(Bb0, Bb1, Ba0, Ba1, 1, ub + 64)
        STEP(Ba0, Ba1, Bb0, Bb1, 2, ub + 96)
        STEP(Bb0, Bb1, Ba0, Ba1, 3, ub + 128)
        STEP(Ba0, Ba1, Bb0, Bb1, 4, ub + 160)
        STEP(Bb0, Bb1, Ba0, Ba1, 5, ub + 192)
        STEP(Ba0, Ba1, Bb0, Bb1, 6, ub + 224)
        STEP(Bb0, Bb1, Ba0, Ba1, 7, ubn)
        f32x4 pv0 = *(const f32x4*)(p01s + uu * 64 + wb * 32 + (l4 << 2));
        f32x4 pv1 = *(const f32x4*)(p01s + uu * 64 + wb * 32 + 16 + (l4 << 2));
        P00 += pv0 * Q00; P01v += pv0 * Q01;
        P10 += pv1 * Q10; P11 += pv1 * Q11;
    }
#undef STEP

    size_t pbase = (size_t)uspl * 128 * 1024;
    {
        int bg0 = bbase + wb * 32 + (l4 << 2);
        int bg1 = bg0 + 16;
        *(f32x4*)(part + pbase + (size_t)y0 * 1024 + bg0) = P00;
        *(f32x4*)(part + pbase + (size_t)y0 * 1024 + bg1) = P10;
        *(f32x4*)(part + pbase + (size_t)(y0 + 16) * 1024 + bg0) = P01v;
        *(f32x4*)(part + pbase + (size_t)(y0 + 16) * 1024 + bg1) = P11;
    }
}

// ---- Kernel D: reduce 32 u-split partials -> out[b*100+y] ------------------
__global__ __launch_bounds__(256) void kD(const float* __restrict__ part,
                                          float* __restrict__ out) {
    int t = threadIdx.x;
    int y = blockIdx.x >> 2;
    int b = ((blockIdx.x & 3) << 8) + t;
    float s = 0.f;
    for (int q = 0; q < 32; ++q)
        s += part[(((size_t)q * 128 + y) << 10) + b];
    out[(size_t)b * 100 + y] = s;
}

extern "C" void kernel_launch(void* const* d_in, const int* in_sizes, int n_in,
                              void* d_out, int out_size, void* d_ws, size_t ws_size,
                              hipStream_t stream) {
    const float* logits = (const float*)d_in[0];
    const float* y_true = (const float*)d_in[1];
    float* out = (float*)d_out;

    char* ws = (char*)d_ws;
    float* P01    = (float*)(ws);                        // 1 MB
    float* P23    = (float*)(ws + (1u << 20));           // 1 MB
    float* P01T   = (float*)(ws + (2u << 20));           // 1 MB
    short* P23s_hi = (short*)(ws + (3u << 20));          // 512 KB
    short* P23s_lo = (short*)(ws + (3u << 20) + (512u << 10)); // 512 KB
    int*   lab    = (int*)(ws + (4u << 20));             // 4 KB
    int*   bidx   = (int*)(ws + (4u << 20) + 4096);
    int*   ylab   = (int*)(ws + (4u << 20) + 8192);
    short* pyT_hi = (short*)(ws + (8u << 20));           // 16 MB (+8 MB wrap slack follows)
    float* part   = (float*)(ws + (40u << 20));          // 16 MB

    kA<<<1024, 256, 0, stream>>>(logits, y_true, P01, P23, P01T, P23s_hi, P23s_lo, lab);
    kS<<<1, 1024, 0, stream>>>(lab, bidx, ylab);
    kB<<<256, 1024, 0, stream>>>(P01, P23, bidx, ylab, pyT_hi);
    kC<<<512, 512, 0, stream>>>(P23s_hi, P23s_lo, P01T, pyT_hi, part);
    kD<<<400, 256, 0, stream>>>(part, out);
}

// Round 7
// 171.190 us; speedup vs baseline: 3.0337x; 1.4070x over previous
//
#include <hip/hip_runtime.h>
#include <hip/hip_bf16.h>

#define EPS 1e-6f

typedef float f32x4 __attribute__((ext_vector_type(4)));
typedef __bf16 bf16x8 __attribute__((ext_vector_type(8)));
typedef short short8 __attribute__((ext_vector_type(8)));

static __device__ __forceinline__ short bf16bits(float x) {
    __hip_bfloat16 h = __float2bfloat16(x);
    short s;
    __builtin_memcpy(&s, &h, 2);
    return s;
}
static __device__ __forceinline__ float bf16back(float x) {
    __hip_bfloat16 h = __float2bfloat16(x);
    return __bfloat162float(h);
}

// ---- Kernel A: softmax + P01/P23 pair products (+transposed/swizzled/split)
__global__ __launch_bounds__(256) void kA(const float* __restrict__ logits,
                                          const float* __restrict__ y_true,
                                          float* __restrict__ P01,
                                          float* __restrict__ P23,
                                          float* __restrict__ P01T,
                                          short* __restrict__ P23s_hi,
                                          short* __restrict__ P23s_lo,
                                          int* __restrict__ label) {
    __shared__ float row[64];
    int b = blockIdx.x, t = threadIdx.x;
    if (t < 64) {
        float x = logits[b * 64 + t];
        float m = x;
        for (int mk = 8; mk >= 1; mk >>= 1) m = fmaxf(m, __shfl_xor(m, mk, 16));
        float e = __expf(x - m);
        float s = e;
        for (int mk = 8; mk >= 1; mk >>= 1) s += __shfl_xor(s, mk, 16);
        row[t] = e / s;
    }
    if (t >= 128 && t < 228) {
        int y = t - 128;
        if (y_true[b * 100 + y] > 0.5f) label[b] = y;
    }
    __syncthreads();
    int hi = t >> 4, lo = t & 15;
    float v01 = row[hi] * row[16 + lo];
    float v23 = row[32 + hi] * row[48 + lo];
    P01[b * 256 + t] = v01;
    P01T[t * 1024 + b] = v01;
    P23[b * 256 + t] = v23;
    float hf = bf16back(v23);
    int ts = t ^ ((b & 7) << 3);   // XOR swizzle (matches kC LDS read)
    P23s_hi[b * 256 + ts] = bf16bits(v23);
    P23s_lo[b * 256 + ts] = bf16bits(v23 - hf);
}

// ---- Kernel S: deterministic counting sort of b by label -------------------
__global__ __launch_bounds__(1024) void kS(const int* __restrict__ label,
                                           int* __restrict__ bidx,
                                           int* __restrict__ ylab) {
    __shared__ int lab[1024];
    __shared__ int offs[101];
    int t = threadIdx.x;
    lab[t] = label[t];
    __syncthreads();
    if (t <= 100) {
        int c = 0;
        for (int b = 0; b < 1024; ++b) c += (lab[b] < t) ? 1 : 0;
        offs[t] = c;
    }
    __syncthreads();
    int my = lab[t];
    int rank = 0;
    for (int b = 0; b < t; ++b) rank += (lab[b] == my) ? 1 : 0;
    int pos = offs[my] + rank;
    bidx[pos] = t;
    ylab[pos] = my;
}

// ---- Kernel B: segmented accumulation -> pyT_hi [y][65536] bf16 ------------
// 1024 threads: 4 b-groups of 256 sorted rows; LDS atomic merge.
__global__ __launch_bounds__(1024) void kB(const float* __restrict__ P01,
                                           const float* __restrict__ P23,
                                           const int* __restrict__ bidx,
                                           const int* __restrict__ ylab,
                                           short* __restrict__ pyT_hi) {
    __shared__ float numy[100 * 257];
    __shared__ float aA[1024];
    __shared__ int blist[1024];
    __shared__ unsigned char yl[1024];
    __shared__ float numjl[4][256];
    int t = threadIdx.x;
    int u = blockIdx.x;

    {
        int b = bidx[t];
        blist[t] = b;
        aA[t] = P01[b * 256 + u];
        yl[t] = (unsigned char)ylab[t];
    }
    for (int i = t; i < 100 * 257; i += 1024) numy[i] = 0.f;
    __syncthreads();

    int g = t >> 8;       // group 0..3
    int tc = t & 255;     // t-column
    int i0 = g << 8;

    float numj = 0.f, acc = 0.f;
    int ycur = yl[i0];
    float v[8];
    #pragma unroll
    for (int k = 0; k < 8; ++k) v[k] = P23[blist[i0 + k] * 256 + tc];

    for (int c = 0; c < 32; ++c) {
        float w[8];
        if (c < 31) {
            #pragma unroll
            for (int k = 0; k < 8; ++k) w[k] = P23[blist[i0 + (c + 1) * 8 + k] * 256 + tc];
        }
        #pragma unroll
        for (int k = 0; k < 8; ++k) {
            int i = i0 + c * 8 + k;
            int y = yl[i];
            if (y != ycur) {
                atomicAdd(&numy[ycur * 257 + tc], acc);
                numj += acc;
                acc = 0.f;
                ycur = y;
            }
            acc = fmaf(aA[i], v[k], acc);
        }
        if (c < 31) {
            #pragma unroll
            for (int k = 0; k < 8; ++k) v[k] = w[k];
        }
    }
    atomicAdd(&numy[ycur * 257 + tc], acc);
    numj += acc;
    numjl[g][tc] = numj;
    __syncthreads();

    // write pyT hi: [y][u*256 + t], packed 2 t's per u32 store
    for (int it = 0; it < 16; ++it) {
        int idx = it * 1024 + t;      // 0..16383
        int y = idx >> 7;             // 0..127
        int t0 = (idx & 127) << 1;
        float v0 = 0.f, v1 = 0.f;
        if (y < 100) {
            float nj0 = fmaxf(numjl[0][t0] + numjl[1][t0] + numjl[2][t0] + numjl[3][t0], EPS);
            float nj1 = fmaxf(numjl[0][t0 + 1] + numjl[1][t0 + 1] + numjl[2][t0 + 1] + numjl[3][t0 + 1], EPS);
            v0 = fminf(fmaxf(numy[y * 257 + t0], EPS) / nj0, 1.0f);
            v1 = fminf(fmaxf(numy[y * 257 + t0 + 1], EPS) / nj1, 1.0f);
        }
        unsigned h0 = (unsigned short)bf16bits(v0);
        unsigned h1 = (unsigned short)bf16bits(v1);
        size_t ei = ((size_t)y * 65536 + (size_t)u * 256 + t0) >> 1;
        ((unsigned*)pyT_hi)[ei] = h0 | (h1 << 16);
    }
}

// ---- Kernel C: MFMA GEMM.  part[uspl][y][b] += P01[b,u]*(py_u x P23^T) -----
// block tile: 64b x 128y x 8u; grid = 16 bb x 32 uspl = 512 blocks (2/CU).
// 512 thr = 8 waves (2 wb x 4 wy), wave tile 32b x 32y.
// __launch_bounds__(512, 2): hipcc's arg2 behaves like CUDA min-blocks/CU;
// (512,4) capped VGPRs at 64 -> spill storm (R4-R6: 0.3-2 GB scratch traffic).
// (512,2) gives the 128-VGPR cap this ~110-reg loop needs; LDS (66 KB) still
// limits to 2 blocks/CU, so occupancy is unchanged.
__global__ __launch_bounds__(512, 2) void kC(const short* __restrict__ P23s_hi,
                                             const short* __restrict__ P23s_lo,
                                             const float* __restrict__ P01T,
                                             const short* __restrict__ pyT_hi,
                                             float* __restrict__ part) {
    __shared__ short Ahi[64 * 256];
    __shared__ short Alo[64 * 256];
    __shared__ float p01s[8 * 64];
    int t = threadIdx.x;
    int bb = blockIdx.x >> 5, uspl = blockIdx.x & 31;
    int bbase = bb << 6;
    int u0 = uspl << 3;

    #pragma unroll
    for (int r = 0; r < 4; ++r) {
        int c = r * 512 + t;   // short8 chunk 0..2047
        *(short8*)(Ahi + c * 8) = *(const short8*)(P23s_hi + bbase * 256 + c * 8);
        *(short8*)(Alo + c * 8) = *(const short8*)(P23s_lo + bbase * 256 + c * 8);
    }
    p01s[t] = P01T[(u0 + (t >> 6)) * 1024 + bbase + (t & 63)];
    __syncthreads();

    int lane = t & 63;
    int wave = t >> 6;
    int wb = wave >> 2, wy = wave & 3;
    int l15 = lane & 15, l4 = lane >> 4;
    int hi8 = l4 << 3;

    int rowA0 = wb * 32 + l15;
    int swz = (rowA0 & 7) << 3;            // same for rowA0+16
    const short* pA0h = Ahi + rowA0 * 256;
    const short* pA0l = Alo + rowA0 * 256;
    const short* pA1h = pA0h + 16 * 256;
    const short* pA1l = pA0l + 16 * 256;

    int y0 = wy * 32 + l15;
    const short* bh0 = pyT_hi + (size_t)y0 * 65536 + hi8;
    const short* bh1 = bh0 + 16 * 65536;

    const f32x4 zero4 = {0.f, 0.f, 0.f, 0.f};
    f32x4 P00 = zero4, P01v = zero4, P10 = zero4, P11 = zero4;
    bf16x8 Ba0, Ba1, Bb0, Bb1;   // named 1-step double buffer (2 n-tiles)

    {   // preload (uu=0, ks=0)
        int off_ = u0 * 256;
        Ba0 = *(const bf16x8*)(bh0 + off_);
        Ba1 = *(const bf16x8*)(bh1 + off_);
    }

#define STEP(CUR0, CUR1, NXT0, NXT1, KS, NOFF)                                   \
    {                                                                            \
        NXT0 = *(const bf16x8*)(bh0 + (NOFF));                                   \
        NXT1 = *(const bf16x8*)(bh1 + (NOFF));                                   \
        int aoff = ((KS) * 32 + hi8) ^ swz;                                      \
        bf16x8 a0h = *(const bf16x8*)(pA0h + aoff);                              \
        bf16x8 a0l = *(const bf16x8*)(pA0l + aoff);                              \
        bf16x8 a1h = *(const bf16x8*)(pA1h + aoff);                              \
        bf16x8 a1l = *(const bf16x8*)(pA1l + aoff);                              \
        f32x4 c00 = ((KS) == 0) ? zero4 : Q00;                                   \
        f32x4 c01 = ((KS) == 0) ? zero4 : Q01;                                   \
        f32x4 c10 = ((KS) == 0) ? zero4 : Q10;                                   \
        f32x4 c11 = ((KS) == 0) ? zero4 : Q11;                                   \
        c00 = __builtin_amdgcn_mfma_f32_16x16x32_bf16(a0h, CUR0, c00, 0, 0, 0);  \
        c10 = __builtin_amdgcn_mfma_f32_16x16x32_bf16(a1h, CUR0, c10, 0, 0, 0);  \
        c01 = __builtin_amdgcn_mfma_f32_16x16x32_bf16(a0h, CUR1, c01, 0, 0, 0);  \
        c11 = __builtin_amdgcn_mfma_f32_16x16x32_bf16(a1h, CUR1, c11, 0, 0, 0);  \
        c00 = __builtin_amdgcn_mfma_f32_16x16x32_bf16(a0l, CUR0, c00, 0, 0, 0);  \
        c10 = __builtin_amdgcn_mfma_f32_16x16x32_bf16(a1l, CUR0, c10, 0, 0, 0);  \
        c01 = __builtin_amdgcn_mfma_f32_16x16x32_bf16(a0l, CUR1, c01, 0, 0, 0);  \
        c11 = __builtin_amdgcn_mfma_f32_16x16x32_bf16(a1l, CUR1, c11, 0, 0, 0);  \
        Q00 = c00; Q01 = c01; Q10 = c10; Q11 = c11;                              \
    }

    #pragma unroll 1
    for (int uu = 0; uu < 8; ++uu) {
        int ub = (u0 + uu) * 256;
        int ubn = ub + 256;   // uu=7 wrap: benign in-workspace prefetch, unused
        f32x4 Q00, Q01, Q10, Q11;
        STEP(Ba0, Ba1, Bb0, Bb1, 0, ub + 32)
        STEP(Bb0, Bb1, Ba0, Ba1, 1, ub + 64)
        STEP(Ba0, Ba1, Bb0, Bb1, 2, ub + 96)
        STEP(Bb0, Bb1, Ba0, Ba1, 3, ub + 128)
        STEP(Ba0, Ba1, Bb0, Bb1, 4, ub + 160)
        STEP(Bb0, Bb1, Ba0, Ba1, 5, ub + 192)
        STEP(Ba0, Ba1, Bb0, Bb1, 6, ub + 224)
        STEP(Bb0, Bb1, Ba0, Ba1, 7, ubn)
        f32x4 pv0 = *(const f32x4*)(p01s + uu * 64 + wb * 32 + (l4 << 2));
        f32x4 pv1 = *(const f32x4*)(p01s + uu * 64 + wb * 32 + 16 + (l4 << 2));
        P00 += pv0 * Q00; P01v += pv0 * Q01;
        P10 += pv1 * Q10; P11 += pv1 * Q11;
    }
#undef STEP

    size_t pbase = (size_t)uspl * 128 * 1024;
    {
        int bg0 = bbase + wb * 32 + (l4 << 2);
        int bg1 = bg0 + 16;
        *(f32x4*)(part + pbase + (size_t)y0 * 1024 + bg0) = P00;
        *(f32x4*)(part + pbase + (size_t)y0 * 1024 + bg1) = P10;
        *(f32x4*)(part + pbase + (size_t)(y0 + 16) * 1024 + bg0) = P01v;
        *(f32x4*)(part + pbase + (size_t)(y0 + 16) * 1024 + bg1) = P11;
    }
}

// ---- Kernel D: reduce 32 u-split partials -> out[b*100+y] ------------------
__global__ __launch_bounds__(256) void kD(const float* __restrict__ part,
                                          float* __restrict__ out) {
    int t = threadIdx.x;
    int y = blockIdx.x >> 2;
    int b = ((blockIdx.x & 3) << 8) + t;
    float s = 0.f;
    for (int q = 0; q < 32; ++q)
        s += part[(((size_t)q * 128 + y) << 10) + b];
    out[(size_t)b * 100 + y] = s;
}

extern "C" void kernel_launch(void* const* d_in, const int* in_sizes, int n_in,
                              void* d_out, int out_size, void* d_ws, size_t ws_size,
                              hipStream_t stream) {
    const float* logits = (const float*)d_in[0];
    const float* y_true = (const float*)d_in[1];
    float* out = (float*)d_out;

    char* ws = (char*)d_ws;
    float* P01    = (float*)(ws);                        // 1 MB
    float* P23    = (float*)(ws + (1u << 20));           // 1 MB
    float* P01T   = (float*)(ws + (2u << 20));           // 1 MB
    short* P23s_hi = (short*)(ws + (3u << 20));          // 512 KB
    short* P23s_lo = (short*)(ws + (3u << 20) + (512u << 10)); // 512 KB
    int*   lab    = (int*)(ws + (4u << 20));             // 4 KB
    int*   bidx   = (int*)(ws + (4u << 20) + 4096);
    int*   ylab   = (int*)(ws + (4u << 20) + 8192);
    short* pyT_hi = (short*)(ws + (8u << 20));           // 16 MB (+slack follows)
    float* part   = (float*)(ws + (40u << 20));          // 16 MB

    kA<<<1024, 256, 0, stream>>>(logits, y_true, P01, P23, P01T, P23s_hi, P23s_lo, lab);
    kS<<<1, 1024, 0, stream>>>(lab, bidx, ylab);
    kB<<<256, 1024, 0, stream>>>(P01, P23, bidx, ylab, pyT_hi);
    kC<<<512, 512, 0, stream>>>(P23s_hi, P23s_lo, P01T, pyT_hi, part);
    kD<<<400, 256, 0, stream>>>(part, out);
}

// Round 8
// 160.737 us; speedup vs baseline: 3.2310x; 1.0650x over previous
//
#include <hip/hip_runtime.h>
#include <hip/hip_bf16.h>

#define EPS 1e-6f

typedef float f32x4 __attribute__((ext_vector_type(4)));
typedef __bf16 bf16x8 __attribute__((ext_vector_type(8)));
typedef short short8 __attribute__((ext_vector_type(8)));

static __device__ __forceinline__ short bf16bits(float x) {
    __hip_bfloat16 h = __float2bfloat16(x);
    short s;
    __builtin_memcpy(&s, &h, 2);
    return s;
}

// ---- Kernel A: softmax + P23 (f32) + P01T (f32) + P23s_hi (bf16, swizzled) -
__global__ __launch_bounds__(256) void kA(const float* __restrict__ logits,
                                          const float* __restrict__ y_true,
                                          float* __restrict__ P23,
                                          float* __restrict__ P01T,
                                          short* __restrict__ P23s_hi,
                                          int* __restrict__ label) {
    __shared__ float row[64];
    int b = blockIdx.x, t = threadIdx.x;
    if (t < 64) {
        float x = logits[b * 64 + t];
        float m = x;
        for (int mk = 8; mk >= 1; mk >>= 1) m = fmaxf(m, __shfl_xor(m, mk, 16));
        float e = __expf(x - m);
        float s = e;
        for (int mk = 8; mk >= 1; mk >>= 1) s += __shfl_xor(s, mk, 16);
        row[t] = e / s;
    }
    if (t >= 128 && t < 228) {
        int y = t - 128;
        if (y_true[b * 100 + y] > 0.5f) label[b] = y;
    }
    __syncthreads();
    int hi = t >> 4, lo = t & 15;
    float v01 = row[hi] * row[16 + lo];
    float v23 = row[32 + hi] * row[48 + lo];
    P01T[t * 1024 + b] = v01;
    P23[b * 256 + t] = v23;
    int ts = t ^ ((b & 7) << 3);   // XOR swizzle (matches kC LDS read)
    P23s_hi[b * 256 + ts] = bf16bits(v23);
}

// ---- Kernel S: deterministic counting sort of b by label -------------------
__global__ __launch_bounds__(1024) void kS(const int* __restrict__ label,
                                           int* __restrict__ bidx,
                                           int* __restrict__ ylab) {
    __shared__ int lab[1024];
    __shared__ int offs[101];
    int t = threadIdx.x;
    lab[t] = label[t];
    __syncthreads();
    if (t <= 100) {
        int c = 0;
        for (int b = 0; b < 1024; ++b) c += (lab[b] < t) ? 1 : 0;
        offs[t] = c;
    }
    __syncthreads();
    int my = lab[t];
    int rank = 0;
    for (int b = 0; b < t; ++b) rank += (lab[b] == my) ? 1 : 0;
    int pos = offs[my] + rank;
    bidx[pos] = t;
    ylab[pos] = my;
}

// ---- Kernel B: segmented accumulation -> pyT_hi [y][65536] bf16 ------------
// 1024 threads: 4 streams of 64 rows per thread (4 independent FMA chains),
// vectorized LDS reads (f32x4 aA, uint2 yl), 32 P23 loads in flight.
__global__ __launch_bounds__(1024, 1) void kB(const float* __restrict__ P01T,
                                              const float* __restrict__ P23,
                                              const int* __restrict__ bidx,
                                              const int* __restrict__ ylab,
                                              short* __restrict__ pyT_hi) {
    __shared__ __align__(16) float numy[100 * 257];
    __shared__ __align__(16) float aA[1024];
    __shared__ __align__(8) unsigned char yl[1024];
    __shared__ float numjl[4][256];
    __shared__ short bl2[1024];
    int t = threadIdx.x;
    int u = blockIdx.x;

    {
        int b = bidx[t];
        bl2[t] = (short)b;
        yl[t] = (unsigned char)ylab[t];
        aA[t] = P01T[u * 1024 + b];   // gather inside one 4KB row (L1-hot)
    }
    for (int i = t; i < 100 * 257; i += 1024) numy[i] = 0.f;
    __syncthreads();

    int g = t >> 8, tc = t & 255;
    int base = g << 8;   // 256 rows per group; 4 streams of 64

    float acc0 = 0.f, acc1 = 0.f, acc2 = 0.f, acc3 = 0.f;
    float nj0 = 0.f, nj1 = 0.f, nj2 = 0.f, nj3 = 0.f;
    int yc0 = yl[base], yc1 = yl[base + 64], yc2 = yl[base + 128], yc3 = yl[base + 192];

    float v[4][8], w[4][8];
    #pragma unroll
    for (int s = 0; s < 4; ++s)
        #pragma unroll
        for (int k = 0; k < 8; ++k)
            v[s][k] = P23[(int)bl2[base + s * 64 + k] * 256 + tc];

    #pragma unroll 1
    for (int c = 0; c < 8; ++c) {
        if (c < 7) {
            #pragma unroll
            for (int s = 0; s < 4; ++s)
                #pragma unroll
                for (int k = 0; k < 8; ++k)
                    w[s][k] = P23[(int)bl2[base + s * 64 + (c + 1) * 8 + k] * 256 + tc];
        }
        int rb = base + c * 8;
        f32x4 a00 = *(const f32x4*)&aA[rb];       f32x4 a01 = *(const f32x4*)&aA[rb + 4];
        f32x4 a10 = *(const f32x4*)&aA[rb + 64];  f32x4 a11 = *(const f32x4*)&aA[rb + 68];
        f32x4 a20 = *(const f32x4*)&aA[rb + 128]; f32x4 a21 = *(const f32x4*)&aA[rb + 132];
        f32x4 a30 = *(const f32x4*)&aA[rb + 192]; f32x4 a31 = *(const f32x4*)&aA[rb + 196];
        uint2 y0p = *(const uint2*)&yl[rb];
        uint2 y1p = *(const uint2*)&yl[rb + 64];
        uint2 y2p = *(const uint2*)&yl[rb + 128];
        uint2 y3p = *(const uint2*)&yl[rb + 192];
        #pragma unroll
        for (int k = 0; k < 8; ++k) {
            const unsigned sh = (unsigned)(k & 3) * 8u;
            int yy0 = (int)(((k < 4 ? y0p.x : y0p.y) >> sh) & 255u);
            int yy1 = (int)(((k < 4 ? y1p.x : y1p.y) >> sh) & 255u);
            int yy2 = (int)(((k < 4 ? y2p.x : y2p.y) >> sh) & 255u);
            int yy3 = (int)(((k < 4 ? y3p.x : y3p.y) >> sh) & 255u);
            float av0 = (k < 4) ? a00[k] : a01[k - 4];
            float av1 = (k < 4) ? a10[k] : a11[k - 4];
            float av2 = (k < 4) ? a20[k] : a21[k - 4];
            float av3 = (k < 4) ? a30[k] : a31[k - 4];
            if (yy0 != yc0) { atomicAdd(&numy[yc0 * 257 + tc], acc0); nj0 += acc0; acc0 = 0.f; yc0 = yy0; }
            acc0 = fmaf(av0, v[0][k], acc0);
            if (yy1 != yc1) { atomicAdd(&numy[yc1 * 257 + tc], acc1); nj1 += acc1; acc1 = 0.f; yc1 = yy1; }
            acc1 = fmaf(av1, v[1][k], acc1);
            if (yy2 != yc2) { atomicAdd(&numy[yc2 * 257 + tc], acc2); nj2 += acc2; acc2 = 0.f; yc2 = yy2; }
            acc2 = fmaf(av2, v[2][k], acc2);
            if (yy3 != yc3) { atomicAdd(&numy[yc3 * 257 + tc], acc3); nj3 += acc3; acc3 = 0.f; yc3 = yy3; }
            acc3 = fmaf(av3, v[3][k], acc3);
        }
        if (c < 7) {
            #pragma unroll
            for (int s = 0; s < 4; ++s)
                #pragma unroll
                for (int k = 0; k < 8; ++k)
                    v[s][k] = w[s][k];
        }
    }
    atomicAdd(&numy[yc0 * 257 + tc], acc0); nj0 += acc0;
    atomicAdd(&numy[yc1 * 257 + tc], acc1); nj1 += acc1;
    atomicAdd(&numy[yc2 * 257 + tc], acc2); nj2 += acc2;
    atomicAdd(&numy[yc3 * 257 + tc], acc3); nj3 += acc3;
    numjl[g][tc] = nj0 + nj1 + nj2 + nj3;
    __syncthreads();

    // write pyT hi: [y][u*256 + t], packed 2 t's per u32 store
    for (int it = 0; it < 16; ++it) {
        int idx = it * 1024 + t;      // 0..16383
        int y = idx >> 7;             // 0..127
        int t0 = (idx & 127) << 1;
        float v0 = 0.f, v1 = 0.f;
        if (y < 100) {
            float nj0s = fmaxf(numjl[0][t0] + numjl[1][t0] + numjl[2][t0] + numjl[3][t0], EPS);
            float nj1s = fmaxf(numjl[0][t0 + 1] + numjl[1][t0 + 1] + numjl[2][t0 + 1] + numjl[3][t0 + 1], EPS);
            v0 = fminf(fmaxf(numy[y * 257 + t0], EPS) / nj0s, 1.0f);
            v1 = fminf(fmaxf(numy[y * 257 + t0 + 1], EPS) / nj1s, 1.0f);
        }
        unsigned h0 = (unsigned short)bf16bits(v0);
        unsigned h1 = (unsigned short)bf16bits(v1);
        size_t ei = ((size_t)y * 65536 + (size_t)u * 256 + t0) >> 1;
        ((unsigned*)pyT_hi)[ei] = h0 | (h1 << 16);
    }
}

// ---- Kernel C: MFMA GEMM.  part[uspl][y][b] += P01[b,u]*(py_u x P23^T) -----
// block tile: 64b x 128y x 8u; grid = 16 bb x 32 uspl = 512 blocks.
// 512 thr = 8 waves (2 wb x 4 wy), wave tile 32b x 32y.
// A = P23 bf16 (single, B=py is already bf16 so A-lo adds nothing) in LDS
// (32 KB, swizzled); B = pyT_hi streamed, named 1-step double buffer.
// (512,2): hipcc arg2 = blocks/CU -> 128-VGPR cap (R7 finding; (512,4)=64 spills).
__global__ __launch_bounds__(512, 2) void kC(const short* __restrict__ P23s_hi,
                                             const float* __restrict__ P01T,
                                             const short* __restrict__ pyT_hi,
                                             float* __restrict__ part) {
    __shared__ short Ahi[64 * 256];
    __shared__ float p01s[8 * 64];
    int t = threadIdx.x;
    int bb = blockIdx.x >> 5, uspl = blockIdx.x & 31;
    int bbase = bb << 6;
    int u0 = uspl << 3;

    #pragma unroll
    for (int r = 0; r < 4; ++r) {
        int c = r * 512 + t;   // short8 chunk 0..2047
        *(short8*)(Ahi + c * 8) = *(const short8*)(P23s_hi + bbase * 256 + c * 8);
    }
    p01s[t] = P01T[(u0 + (t >> 6)) * 1024 + bbase + (t & 63)];
    __syncthreads();

    int lane = t & 63;
    int wave = t >> 6;
    int wb = wave >> 2, wy = wave & 3;
    int l15 = lane & 15, l4 = lane >> 4;
    int hi8 = l4 << 3;

    int rowA0 = wb * 32 + l15;
    int swz = (rowA0 & 7) << 3;            // same for rowA0+16
    const short* pA0h = Ahi + rowA0 * 256;
    const short* pA1h = pA0h + 16 * 256;

    int y0 = wy * 32 + l15;
    const short* bh0 = pyT_hi + (size_t)y0 * 65536 + hi8;
    const short* bh1 = bh0 + 16 * 65536;

    const f32x4 zero4 = {0.f, 0.f, 0.f, 0.f};
    f32x4 P00 = zero4, P01v = zero4, P10 = zero4, P11 = zero4;
    bf16x8 Ba0, Ba1, Bb0, Bb1;   // named 1-step double buffer (2 n-tiles)

    {   // preload (uu=0, ks=0)
        int off_ = u0 * 256;
        Ba0 = *(const bf16x8*)(bh0 + off_);
        Ba1 = *(const bf16x8*)(bh1 + off_);
    }

#define STEP(CUR0, CUR1, NXT0, NXT1, KS, NOFF)                                   \
    {                                                                            \
        NXT0 = *(const bf16x8*)(bh0 + (NOFF));                                   \
        NXT1 = *(const bf16x8*)(bh1 + (NOFF));                                   \
        int aoff = ((KS) * 32 + hi8) ^ swz;                                      \
        bf16x8 a0h = *(const bf16x8*)(pA0h + aoff);                              \
        bf16x8 a1h = *(const bf16x8*)(pA1h + aoff);                              \
        f32x4 c00 = ((KS) == 0) ? zero4 : Q00;                                   \
        f32x4 c01 = ((KS) == 0) ? zero4 : Q01;                                   \
        f32x4 c10 = ((KS) == 0) ? zero4 : Q10;                                   \
        f32x4 c11 = ((KS) == 0) ? zero4 : Q11;                                   \
        c00 = __builtin_amdgcn_mfma_f32_16x16x32_bf16(a0h, CUR0, c00, 0, 0, 0);  \
        c10 = __builtin_amdgcn_mfma_f32_16x16x32_bf16(a1h, CUR0, c10, 0, 0, 0);  \
        c01 = __builtin_amdgcn_mfma_f32_16x16x32_bf16(a0h, CUR1, c01, 0, 0, 0);  \
        c11 = __builtin_amdgcn_mfma_f32_16x16x32_bf16(a1h, CUR1, c11, 0, 0, 0);  \
        Q00 = c00; Q01 = c01; Q10 = c10; Q11 = c11;                              \
    }

    #pragma unroll 1
    for (int uu = 0; uu < 8; ++uu) {
        int ub = (u0 + uu) * 256;
        int ubn = ub + 256;   // uu=7 wrap: benign in-workspace prefetch, unused
        f32x4 Q00, Q01, Q10, Q11;
        STEP(Ba0, Ba1, Bb0, Bb1, 0, ub + 32)
        STEP(Bb0, Bb1, Ba0, Ba1, 1, ub + 64)
        STEP(Ba0, Ba1, Bb0, Bb1, 2, ub + 96)
        STEP(Bb0, Bb1, Ba0, Ba1, 3, ub + 128)
        STEP(Ba0, Ba1, Bb0, Bb1, 4, ub + 160)
        STEP(Bb0, Bb1, Ba0, Ba1, 5, ub + 192)
        STEP(Ba0, Ba1, Bb0, Bb1, 6, ub + 224)
        STEP(Bb0, Bb1, Ba0, Ba1, 7, ubn)
        f32x4 pv0 = *(const f32x4*)(p01s + uu * 64 + wb * 32 + (l4 << 2));
        f32x4 pv1 = *(const f32x4*)(p01s + uu * 64 + wb * 32 + 16 + (l4 << 2));
        P00 += pv0 * Q00; P01v += pv0 * Q01;
        P10 += pv1 * Q10; P11 += pv1 * Q11;
    }
#undef STEP

    size_t pbase = (size_t)uspl * 128 * 1024;
    {
        int bg0 = bbase + wb * 32 + (l4 << 2);
        int bg1 = bg0 + 16;
        *(f32x4*)(part + pbase + (size_t)y0 * 1024 + bg0) = P00;
        *(f32x4*)(part + pbase + (size_t)y0 * 1024 + bg1) = P10;
        *(f32x4*)(part + pbase + (size_t)(y0 + 16) * 1024 + bg0) = P01v;
        *(f32x4*)(part + pbase + (size_t)(y0 + 16) * 1024 + bg1) = P11;
    }
}

// ---- Kernel D: reduce 32 u-split partials -> out[b*100+y] ------------------
__global__ __launch_bounds__(256) void kD(const float* __restrict__ part,
                                          float* __restrict__ out) {
    int t = threadIdx.x;
    int y = blockIdx.x >> 2;
    int b = ((blockIdx.x & 3) << 8) + t;
    float s = 0.f;
    for (int q = 0; q < 32; ++q)
        s += part[(((size_t)q * 128 + y) << 10) + b];
    out[(size_t)b * 100 + y] = s;
}

extern "C" void kernel_launch(void* const* d_in, const int* in_sizes, int n_in,
                              void* d_out, int out_size, void* d_ws, size_t ws_size,
                              hipStream_t stream) {
    const float* logits = (const float*)d_in[0];
    const float* y_true = (const float*)d_in[1];
    float* out = (float*)d_out;

    char* ws = (char*)d_ws;
    float* P23    = (float*)(ws + (1u << 20));           // 1 MB
    float* P01T   = (float*)(ws + (2u << 20));           // 1 MB
    short* P23s_hi = (short*)(ws + (3u << 20));          // 512 KB
    int*   lab    = (int*)(ws + (4u << 20));             // 4 KB
    int*   bidx   = (int*)(ws + (4u << 20) + 4096);
    int*   ylab   = (int*)(ws + (4u << 20) + 8192);
    short* pyT_hi = (short*)(ws + (8u << 20));           // 16 MB (+slack follows)
    float* part   = (float*)(ws + (40u << 20));          // 16 MB

    kA<<<1024, 256, 0, stream>>>(logits, y_true, P23, P01T, P23s_hi, lab);
    kS<<<1, 1024, 0, stream>>>(lab, bidx, ylab);
    kB<<<256, 1024, 0, stream>>>(P01T, P23, bidx, ylab, pyT_hi);
    kC<<<512, 512, 0, stream>>>(P23s_hi, P01T, pyT_hi, part);
    kD<<<400, 256, 0, stream>>>(part, out);
}

// Round 9
// 160.565 us; speedup vs baseline: 3.2345x; 1.0011x over previous
//
#include <hip/hip_runtime.h>
#include <hip/hip_bf16.h>

#define EPS 1e-6f

typedef float f32x4 __attribute__((ext_vector_type(4)));
typedef __bf16 bf16x8 __attribute__((ext_vector_type(8)));
typedef short short8 __attribute__((ext_vector_type(8)));

static __device__ __forceinline__ short bf16bits(float x) {
    __hip_bfloat16 h = __float2bfloat16(x);
    short s;
    __builtin_memcpy(&s, &h, 2);
    return s;
}

// ---- Kernel A: softmax + P23 (f32) + P01T (f32) + P23s_hi (bf16, swizzled) -
__global__ __launch_bounds__(256) void kA(const float* __restrict__ logits,
                                          const float* __restrict__ y_true,
                                          float* __restrict__ P23,
                                          float* __restrict__ P01T,
                                          short* __restrict__ P23s_hi,
                                          int* __restrict__ label) {
    __shared__ float row[64];
    int b = blockIdx.x, t = threadIdx.x;
    if (t < 64) {
        float x = logits[b * 64 + t];
        float m = x;
        for (int mk = 8; mk >= 1; mk >>= 1) m = fmaxf(m, __shfl_xor(m, mk, 16));
        float e = __expf(x - m);
        float s = e;
        for (int mk = 8; mk >= 1; mk >>= 1) s += __shfl_xor(s, mk, 16);
        row[t] = e / s;
    }
    if (t >= 128 && t < 228) {
        int y = t - 128;
        if (y_true[b * 100 + y] > 0.5f) label[b] = y;
    }
    __syncthreads();
    int hi = t >> 4, lo = t & 15;
    float v01 = row[hi] * row[16 + lo];
    float v23 = row[32 + hi] * row[48 + lo];
    P01T[t * 1024 + b] = v01;
    P23[b * 256 + t] = v23;
    int ts = t ^ ((b & 7) << 3);   // XOR swizzle (matches kC LDS read)
    P23s_hi[b * 256 + ts] = bf16bits(v23);
}

// ---- Kernel S: deterministic counting sort of b by label -------------------
__global__ __launch_bounds__(1024) void kS(const int* __restrict__ label,
                                           int* __restrict__ bidx,
                                           int* __restrict__ ylab) {
    __shared__ int lab[1024];
    __shared__ int offs[101];
    int t = threadIdx.x;
    lab[t] = label[t];
    __syncthreads();
    if (t <= 100) {
        int c = 0;
        for (int b = 0; b < 1024; ++b) c += (lab[b] < t) ? 1 : 0;
        offs[t] = c;
    }
    __syncthreads();
    int my = lab[t];
    int rank = 0;
    for (int b = 0; b < t; ++b) rank += (lab[b] == my) ? 1 : 0;
    int pos = offs[my] + rank;
    bidx[pos] = t;
    ylab[pos] = my;
}

// ---- Kernel B: segmented accumulation -> pyT_hi [y][65536] bf16 ------------
// 1024 threads: 4 streams of 64 rows per thread (4 independent FMA chains),
// vectorized LDS reads (f32x4 aA, uint2 yl), 32 P23 loads in flight.
__global__ __launch_bounds__(1024, 1) void kB(const float* __restrict__ P01T,
                                              const float* __restrict__ P23,
                                              const int* __restrict__ bidx,
                                              const int* __restrict__ ylab,
                                              short* __restrict__ pyT_hi) {
    __shared__ __align__(16) float numy[100 * 257];
    __shared__ __align__(16) float aA[1024];
    __shared__ __align__(8) unsigned char yl[1024];
    __shared__ float numjl[4][256];
    __shared__ short bl2[1024];
    int t = threadIdx.x;
    int u = blockIdx.x;

    {
        int b = bidx[t];
        bl2[t] = (short)b;
        yl[t] = (unsigned char)ylab[t];
        aA[t] = P01T[u * 1024 + b];   // gather inside one 4KB row (L1-hot)
    }
    for (int i = t; i < 100 * 257; i += 1024) numy[i] = 0.f;
    __syncthreads();

    int g = t >> 8, tc = t & 255;
    int base = g << 8;   // 256 rows per group; 4 streams of 64

    float acc0 = 0.f, acc1 = 0.f, acc2 = 0.f, acc3 = 0.f;
    float nj0 = 0.f, nj1 = 0.f, nj2 = 0.f, nj3 = 0.f;
    int yc0 = yl[base], yc1 = yl[base + 64], yc2 = yl[base + 128], yc3 = yl[base + 192];

    float v[4][8], w[4][8];
    #pragma unroll
    for (int s = 0; s < 4; ++s)
        #pragma unroll
        for (int k = 0; k < 8; ++k)
            v[s][k] = P23[(int)bl2[base + s * 64 + k] * 256 + tc];

    #pragma unroll 1
    for (int c = 0; c < 8; ++c) {
        if (c < 7) {
            #pragma unroll
            for (int s = 0; s < 4; ++s)
                #pragma unroll
                for (int k = 0; k < 8; ++k)
                    w[s][k] = P23[(int)bl2[base + s * 64 + (c + 1) * 8 + k] * 256 + tc];
        }
        int rb = base + c * 8;
        f32x4 a00 = *(const f32x4*)&aA[rb];       f32x4 a01 = *(const f32x4*)&aA[rb + 4];
        f32x4 a10 = *(const f32x4*)&aA[rb + 64];  f32x4 a11 = *(const f32x4*)&aA[rb + 68];
        f32x4 a20 = *(const f32x4*)&aA[rb + 128]; f32x4 a21 = *(const f32x4*)&aA[rb + 132];
        f32x4 a30 = *(const f32x4*)&aA[rb + 192]; f32x4 a31 = *(const f32x4*)&aA[rb + 196];
        uint2 y0p = *(const uint2*)&yl[rb];
        uint2 y1p = *(const uint2*)&yl[rb + 64];
        uint2 y2p = *(const uint2*)&yl[rb + 128];
        uint2 y3p = *(const uint2*)&yl[rb + 192];
        #pragma unroll
        for (int k = 0; k < 8; ++k) {
            const unsigned sh = (unsigned)(k & 3) * 8u;
            int yy0 = (int)(((k < 4 ? y0p.x : y0p.y) >> sh) & 255u);
            int yy1 = (int)(((k < 4 ? y1p.x : y1p.y) >> sh) & 255u);
            int yy2 = (int)(((k < 4 ? y2p.x : y2p.y) >> sh) & 255u);
            int yy3 = (int)(((k < 4 ? y3p.x : y3p.y) >> sh) & 255u);
            float av0 = (k < 4) ? a00[k] : a01[k - 4];
            float av1 = (k < 4) ? a10[k] : a11[k - 4];
            float av2 = (k < 4) ? a20[k] : a21[k - 4];
            float av3 = (k < 4) ? a30[k] : a31[k - 4];
            if (yy0 != yc0) { atomicAdd(&numy[yc0 * 257 + tc], acc0); nj0 += acc0; acc0 = 0.f; yc0 = yy0; }
            acc0 = fmaf(av0, v[0][k], acc0);
            if (yy1 != yc1) { atomicAdd(&numy[yc1 * 257 + tc], acc1); nj1 += acc1; acc1 = 0.f; yc1 = yy1; }
            acc1 = fmaf(av1, v[1][k], acc1);
            if (yy2 != yc2) { atomicAdd(&numy[yc2 * 257 + tc], acc2); nj2 += acc2; acc2 = 0.f; yc2 = yy2; }
            acc2 = fmaf(av2, v[2][k], acc2);
            if (yy3 != yc3) { atomicAdd(&numy[yc3 * 257 + tc], acc3); nj3 += acc3; acc3 = 0.f; yc3 = yy3; }
            acc3 = fmaf(av3, v[3][k], acc3);
        }
        if (c < 7) {
            #pragma unroll
            for (int s = 0; s < 4; ++s)
                #pragma unroll
                for (int k = 0; k < 8; ++k)
                    v[s][k] = w[s][k];
        }
    }
    atomicAdd(&numy[yc0 * 257 + tc], acc0); nj0 += acc0;
    atomicAdd(&numy[yc1 * 257 + tc], acc1); nj1 += acc1;
    atomicAdd(&numy[yc2 * 257 + tc], acc2); nj2 += acc2;
    atomicAdd(&numy[yc3 * 257 + tc], acc3); nj3 += acc3;
    numjl[g][tc] = nj0 + nj1 + nj2 + nj3;
    __syncthreads();

    // write pyT hi: [y][u*256 + t], packed 2 t's per u32 store
    for (int it = 0; it < 16; ++it) {
        int idx = it * 1024 + t;      // 0..16383
        int y = idx >> 7;             // 0..127
        int t0 = (idx & 127) << 1;
        float v0 = 0.f, v1 = 0.f;
        if (y < 100) {
            float nj0s = fmaxf(numjl[0][t0] + numjl[1][t0] + numjl[2][t0] + numjl[3][t0], EPS);
            float nj1s = fmaxf(numjl[0][t0 + 1] + numjl[1][t0 + 1] + numjl[2][t0 + 1] + numjl[3][t0 + 1], EPS);
            v0 = fminf(fmaxf(numy[y * 257 + t0], EPS) / nj0s, 1.0f);
            v1 = fminf(fmaxf(numy[y * 257 + t0 + 1], EPS) / nj1s, 1.0f);
        }
        unsigned h0 = (unsigned short)bf16bits(v0);
        unsigned h1 = (unsigned short)bf16bits(v1);
        size_t ei = ((size_t)y * 65536 + (size_t)u * 256 + t0) >> 1;
        ((unsigned*)pyT_hi)[ei] = h0 | (h1 << 16);
    }
}

// ---- Kernel C: MFMA GEMM.  part[uspl][y][b] += P01[b,u]*(py_u x P23^T) -----
// block tile: 64b x 128y x 8u; grid = 16 bb x 32 uspl = 512 blocks.
// 512 thr = 8 waves (2 wb x 4 wy), wave tile 32b x 32y.
// A = P23 bf16 in LDS (32 KB, swizzled); B = pyT_hi streamed via a 4-set
// NAMED buffer rotation (W/X/Y/Z) = 3-step lookahead: at step s consume s%4,
// load s+3 into (s+3)%4 (freed at s-1). 8 steps % 4 == 0 -> roles are
// loop-invariant, all indices static (no scratch demotion).
// (512,2): hipcc arg2 = blocks/CU -> 128-VGPR cap (R7 finding; (512,4)=64 spills).
__global__ __launch_bounds__(512, 2) void kC(const short* __restrict__ P23s_hi,
                                             const float* __restrict__ P01T,
                                             const short* __restrict__ pyT_hi,
                                             float* __restrict__ part) {
    __shared__ short Ahi[64 * 256];
    __shared__ float p01s[8 * 64];
    int t = threadIdx.x;
    int bb = blockIdx.x >> 5, uspl = blockIdx.x & 31;
    int bbase = bb << 6;
    int u0 = uspl << 3;

    #pragma unroll
    for (int r = 0; r < 4; ++r) {
        int c = r * 512 + t;   // short8 chunk 0..2047
        *(short8*)(Ahi + c * 8) = *(const short8*)(P23s_hi + bbase * 256 + c * 8);
    }
    p01s[t] = P01T[(u0 + (t >> 6)) * 1024 + bbase + (t & 63)];
    __syncthreads();

    int lane = t & 63;
    int wave = t >> 6;
    int wb = wave >> 2, wy = wave & 3;
    int l15 = lane & 15, l4 = lane >> 4;
    int hi8 = l4 << 3;

    int rowA0 = wb * 32 + l15;
    int swz = (rowA0 & 7) << 3;            // same for rowA0+16
    const short* pA0h = Ahi + rowA0 * 256;
    const short* pA1h = pA0h + 16 * 256;

    int y0 = wy * 32 + l15;
    const short* bh0 = pyT_hi + (size_t)y0 * 65536 + hi8;
    const short* bh1 = bh0 + 16 * 65536;

    const f32x4 zero4 = {0.f, 0.f, 0.f, 0.f};
    f32x4 P00 = zero4, P01v = zero4, P10 = zero4, P11 = zero4;
    bf16x8 W0, W1, X0, X1, Y0, Y1, Z0, Z1;   // 4 named buffer sets

#define LOADB(B0, B1, NOFF)                     \
    {                                           \
        B0 = *(const bf16x8*)(bh0 + (NOFF));    \
        B1 = *(const bf16x8*)(bh1 + (NOFF));    \
    }

#define STEP(CUR0, CUR1, NXT0, NXT1, KS, NOFF)                                   \
    {                                                                            \
        LOADB(NXT0, NXT1, NOFF)                                                  \
        int aoff = ((KS) * 32 + hi8) ^ swz;                                      \
        bf16x8 a0h = *(const bf16x8*)(pA0h + aoff);                              \
        bf16x8 a1h = *(const bf16x8*)(pA1h + aoff);                              \
        f32x4 c00 = ((KS) == 0) ? zero4 : Q00;                                   \
        f32x4 c01 = ((KS) == 0) ? zero4 : Q01;                                   \
        f32x4 c10 = ((KS) == 0) ? zero4 : Q10;                                   \
        f32x4 c11 = ((KS) == 0) ? zero4 : Q11;                                   \
        c00 = __builtin_amdgcn_mfma_f32_16x16x32_bf16(a0h, CUR0, c00, 0, 0, 0);  \
        c10 = __builtin_amdgcn_mfma_f32_16x16x32_bf16(a1h, CUR0, c10, 0, 0, 0);  \
        c01 = __builtin_amdgcn_mfma_f32_16x16x32_bf16(a0h, CUR1, c01, 0, 0, 0);  \
        c11 = __builtin_amdgcn_mfma_f32_16x16x32_bf16(a1h, CUR1, c11, 0, 0, 0);  \
        Q00 = c00; Q01 = c01; Q10 = c10; Q11 = c11;                              \
    }

    {   // preload ks0..ks2 of uu=0 (lookahead 3)
        int ub0 = u0 * 256;
        LOADB(W0, W1, ub0)
        LOADB(X0, X1, ub0 + 32)
        LOADB(Y0, Y1, ub0 + 64)
    }

    #pragma unroll 1
    for (int uu = 0; uu < 8; ++uu) {
        int ub = (u0 + uu) * 256;
        int ubn = ub + 256;   // uu=7: wraps <=600B past pyT end, inside ws slack
        f32x4 Q00, Q01, Q10, Q11;
        STEP(W0, W1, Z0, Z1, 0, ub + 96)    // load ks3
        STEP(X0, X1, W0, W1, 1, ub + 128)   // load ks4
        STEP(Y0, Y1, X0, X1, 2, ub + 160)   // load ks5
        STEP(Z0, Z1, Y0, Y1, 3, ub + 192)   // load ks6
        STEP(W0, W1, Z0, Z1, 4, ub + 224)   // load ks7
        STEP(X0, X1, W0, W1, 5, ubn)        // load next ks0
        STEP(Y0, Y1, X0, X1, 6, ubn + 32)   // load next ks1
        STEP(Z0, Z1, Y0, Y1, 7, ubn + 64)   // load next ks2
        f32x4 pv0 = *(const f32x4*)(p01s + uu * 64 + wb * 32 + (l4 << 2));
        f32x4 pv1 = *(const f32x4*)(p01s + uu * 64 + wb * 32 + 16 + (l4 << 2));
        P00 += pv0 * Q00; P01v += pv0 * Q01;
        P10 += pv1 * Q10; P11 += pv1 * Q11;
    }
#undef STEP
#undef LOADB

    size_t pbase = (size_t)uspl * 128 * 1024;
    {
        int bg0 = bbase + wb * 32 + (l4 << 2);
        int bg1 = bg0 + 16;
        *(f32x4*)(part + pbase + (size_t)y0 * 1024 + bg0) = P00;
        *(f32x4*)(part + pbase + (size_t)y0 * 1024 + bg1) = P10;
        *(f32x4*)(part + pbase + (size_t)(y0 + 16) * 1024 + bg0) = P01v;
        *(f32x4*)(part + pbase + (size_t)(y0 + 16) * 1024 + bg1) = P11;
    }
}

// ---- Kernel D: reduce 32 u-split partials -> out[b*100+y] ------------------
__global__ __launch_bounds__(256) void kD(const float* __restrict__ part,
                                          float* __restrict__ out) {
    int t = threadIdx.x;
    int y = blockIdx.x >> 2;
    int b = ((blockIdx.x & 3) << 8) + t;
    float s = 0.f;
    for (int q = 0; q < 32; ++q)
        s += part[(((size_t)q * 128 + y) << 10) + b];
    out[(size_t)b * 100 + y] = s;
}

extern "C" void kernel_launch(void* const* d_in, const int* in_sizes, int n_in,
                              void* d_out, int out_size, void* d_ws, size_t ws_size,
                              hipStream_t stream) {
    const float* logits = (const float*)d_in[0];
    const float* y_true = (const float*)d_in[1];
    float* out = (float*)d_out;

    char* ws = (char*)d_ws;
    float* P23    = (float*)(ws + (1u << 20));           // 1 MB
    float* P01T   = (float*)(ws + (2u << 20));           // 1 MB
    short* P23s_hi = (short*)(ws + (3u << 20));          // 512 KB
    int*   lab    = (int*)(ws + (4u << 20));             // 4 KB
    int*   bidx   = (int*)(ws + (4u << 20) + 4096);
    int*   ylab   = (int*)(ws + (4u << 20) + 8192);
    short* pyT_hi = (short*)(ws + (8u << 20));           // 16 MB (+slack follows)
    float* part   = (float*)(ws + (40u << 20));          // 16 MB

    kA<<<1024, 256, 0, stream>>>(logits, y_true, P23, P01T, P23s_hi, lab);
    kS<<<1, 1024, 0, stream>>>(lab, bidx, ylab);
    kB<<<256, 1024, 0, stream>>>(P01T, P23, bidx, ylab, pyT_hi);
    kC<<<512, 512, 0, stream>>>(P23s_hi, P01T, pyT_hi, part);
    kD<<<400, 256, 0, stream>>>(part, out);
}